// Round 1
// baseline (403.019 us; speedup 1.0000x reference)
//
#include <hip/hip_runtime.h>

// Bloch RK4 trajectory integrator.
// B=65536 independent 3-state linear ODEs, T=512 outputs (incl. y0), RK4.
// One thread per system; state in registers; dt values staged in LDS with a
// one-ahead prefetch so the ds_read latency never sits on the critical path.
// Memory-bound on the 402.7 MB output stream.

#define NB 65536
#define NT 512

__global__ __launch_bounds__(256) void bloch_rk4_kernel(
    const float* __restrict__ y0,
    const float* __restrict__ tspan,
    const float* __restrict__ params,
    float* __restrict__ out)
{
    __shared__ float sdt[NT];  // sdt[i] = tspan[i+1]-tspan[i], sdt[NT-1]=0 (pad)
    const int tid = threadIdx.x;
    for (int i = tid; i < NT; i += 256) {
        float d = 0.0f;
        if (i < NT - 1) d = tspan[i + 1] - tspan[i];
        sdt[i] = d;
    }
    __syncthreads();

    const int b   = blockIdx.x * 256 + tid;
    const int ib3 = b * 3;

    float u = y0[ib3 + 0];
    float v = y0[ib3 + 1];
    float w = y0[ib3 + 2];
    const float Om = params[ib3 + 0];
    const float g  = params[ib3 + 2];
    const float g2 = 2.0f * g;

    // t = 0 output is y0 itself
    out[ib3 + 0] = u;
    out[ib3 + 1] = v;
    out[ib3 + 2] = w;

    float dt = sdt[0];
    for (int i = 1; i < NT; ++i) {
        const float dt_next = sdt[i];  // prefetch next dt (hidden behind compute)

        // k1 = f(y)
        const float k1u = -g * u;
        const float k1v = -g * v - Om * w;
        const float k1w = Om * v - g2 * w - g2;

        const float h = 0.5f * dt;
        float uu = u + h * k1u;
        float vv = v + h * k1v;
        float ww = w + h * k1w;

        // k2 = f(y + dt/2 * k1)
        const float k2u = -g * uu;
        const float k2v = -g * vv - Om * ww;
        const float k2w = Om * vv - g2 * ww - g2;

        uu = u + h * k2u;
        vv = v + h * k2v;
        ww = w + h * k2w;

        // k3 = f(y + dt/2 * k2)
        const float k3u = -g * uu;
        const float k3v = -g * vv - Om * ww;
        const float k3w = Om * vv - g2 * ww - g2;

        uu = u + dt * k3u;
        vv = v + dt * k3v;
        ww = w + dt * k3w;

        // k4 = f(y + dt * k3)
        const float k4u = -g * uu;
        const float k4v = -g * vv - Om * ww;
        const float k4w = Om * vv - g2 * ww - g2;

        const float s = dt * (1.0f / 6.0f);
        u += s * (k1u + 2.0f * k2u + 2.0f * k3u + k4u);
        v += s * (k1v + 2.0f * k2v + 2.0f * k3v + k4v);
        w += s * (k1w + 2.0f * k2w + 2.0f * k3w + k4w);

        const size_t o = (size_t)i * (NB * 3) + (size_t)ib3;
        out[o + 0] = u;
        out[o + 1] = v;
        out[o + 2] = w;

        dt = dt_next;
    }
}

extern "C" void kernel_launch(void* const* d_in, const int* in_sizes, int n_in,
                              void* d_out, int out_size, void* d_ws, size_t ws_size,
                              hipStream_t stream) {
    const float* y0     = (const float*)d_in[0];
    const float* tspan  = (const float*)d_in[1];
    const float* params = (const float*)d_in[2];
    float* out = (float*)d_out;

    bloch_rk4_kernel<<<NB / 256, 256, 0, stream>>>(y0, tspan, params, out);
}